// Round 1
// baseline (482.297 us; speedup 1.0000x reference)
//
#include <hip/hip_runtime.h>

// Problem constants (match reference)
#define Bq   4
#define Cc   64
#define Hh   160
#define Ww   160
#define HWp  (Hh * Ww)          // 25600
#define COUTc 64
#define OFFC 18                 // 2*K*K offset channels

// Workspace layout (float offsets)
#define WT_OFS     0                         // wT  [c*9+k][64]   : 36864 floats
#define WTOFF_OFS  (64 * 576)                // wToff[c*9+tap][18]: 10368 floats
#define OFF_OFS    (WTOFF_OFS + 18 * 576)    // offsets [b][18][H][W]: 1843200 floats
// total ~7.56 MB of d_ws

// ---------------------------------------------------------------------------
// Prep: transpose weights so inner loops read contiguous, wave-uniform floats
// w     [o][c][ky][kx] (o<64)  -> wT   [(c*9+k)*64 + o]
// w_off [oc][c][ky][kx] (oc<18)-> wToff[(c*9+k)*18 + oc]
// ---------------------------------------------------------------------------
__global__ __launch_bounds__(256) void prep_kernel(const float* __restrict__ w,
                                                   const float* __restrict__ w_off,
                                                   float* __restrict__ ws) {
    int i = blockIdx.x * 256 + threadIdx.x;
    float* wT    = ws + WT_OFS;
    float* wToff = ws + WTOFF_OFS;
    if (i < 64 * 576) {
        int o  = i / 576;
        int ck = i - o * 576;          // c*9 + k
        wT[ck * 64 + o] = w[i];
    }
    if (i < 18 * 576) {
        int oc = i / 576;
        int ck = i - oc * 576;
        wToff[ck * 18 + oc] = w_off[i];
    }
}

// ---------------------------------------------------------------------------
// Offset conv: offset[b][oc][y][x] = b_off[oc] + sum_{c,ky,kx} x * w_off
// One thread per output pixel, acc[18] in registers.
// ---------------------------------------------------------------------------
__global__ __launch_bounds__(64) void off_conv_kernel(const float* __restrict__ x,
                                                      const float* __restrict__ b_off,
                                                      const float* __restrict__ ws_ro,
                                                      float* __restrict__ off_out) {
    int idx = blockIdx.x * 64 + threadIdx.x;     // 102400 threads
    int xw  = idx % Ww;
    int t   = idx / Ww;
    int y   = t % Hh;
    int b   = t / Hh;

    const float* wToff = ws_ro + WTOFF_OFS;
    float acc[OFFC];
#pragma unroll
    for (int oc = 0; oc < OFFC; ++oc) acc[oc] = b_off[oc];

    const float* xb = x + (size_t)b * Cc * HWp;

    for (int ky = 0; ky < 3; ++ky) {
        int yy = y - 1 + ky;
        if (yy < 0 || yy >= Hh) continue;
        for (int kx = 0; kx < 3; ++kx) {
            int xx = xw - 1 + kx;
            if (xx < 0 || xx >= Ww) continue;
            const float* xp = xb + yy * Ww + xx;
            const float* wp = wToff + (ky * 3 + kx) * 18;
            for (int c = 0; c < Cc; ++c) {
                float xv = xp[c * HWp];
                const float* w2 = wp + c * 9 * 18;   // uniform address -> s_load
#pragma unroll
                for (int oc = 0; oc < OFFC; ++oc)
                    acc[oc] += xv * w2[oc];
            }
        }
    }

    int pix = y * Ww + xw;
#pragma unroll
    for (int oc = 0; oc < OFFC; ++oc)
        off_out[((size_t)b * OFFC + oc) * HWp + pix] = acc[oc];
}

// ---------------------------------------------------------------------------
// Deformable conv main: one thread per output pixel, acc[64] output channels.
// Precompute 9 taps (4 clamped linear idx + 4 masked bilinear weights), then
// per input channel: gather-sample 9 values, 576 FMAs against uniform s_load
// weights.
// ---------------------------------------------------------------------------
__global__ __launch_bounds__(64) void deform_kernel(const float* __restrict__ x,
                                                    const float* __restrict__ bias,
                                                    const float* __restrict__ ws_ro,
                                                    float* __restrict__ out) {
    int idx = blockIdx.x * 64 + threadIdx.x;     // 102400 threads
    int xw  = idx % Ww;
    int t   = idx / Ww;
    int y   = t % Hh;
    int b   = t / Hh;

    const float* off = ws_ro + OFF_OFS + (size_t)b * OFFC * HWp;
    const float* wT  = ws_ro + WT_OFS;
    int pix = y * Ww + xw;

    int   lin[9][4];
    float wgt[9][4];
#pragma unroll
    for (int k = 0; k < 9; ++k) {
        int ky = k / 3, kx = k % 3;
        float dy = off[(2 * k) * HWp + pix];
        float dx = off[(2 * k + 1) * HWp + pix];
        float py = (float)(y - 1 + ky) + dy;
        float px = (float)(xw - 1 + kx) + dx;
        float fy0 = floorf(py), fx0 = floorf(px);
        float ly = py - fy0, lx = px - fx0;
        int iy0 = (int)fy0, ix0 = (int)fx0;
        int iy1 = iy0 + 1,  ix1 = ix0 + 1;
        bool vy0 = (iy0 >= 0) && (iy0 < Hh);
        bool vy1 = (iy1 >= 0) && (iy1 < Hh);
        bool vx0 = (ix0 >= 0) && (ix0 < Ww);
        bool vx1 = (ix1 >= 0) && (ix1 < Ww);
        int cy0 = min(max(iy0, 0), Hh - 1), cy1 = min(max(iy1, 0), Hh - 1);
        int cx0 = min(max(ix0, 0), Ww - 1), cx1 = min(max(ix1, 0), Ww - 1);
        lin[k][0] = cy0 * Ww + cx0;
        lin[k][1] = cy0 * Ww + cx1;
        lin[k][2] = cy1 * Ww + cx0;
        lin[k][3] = cy1 * Ww + cx1;
        wgt[k][0] = (vy0 && vx0) ? (1.f - ly) * (1.f - lx) : 0.f;
        wgt[k][1] = (vy0 && vx1) ? (1.f - ly) * lx        : 0.f;
        wgt[k][2] = (vy1 && vx0) ? ly * (1.f - lx)        : 0.f;
        wgt[k][3] = (vy1 && vx1) ? ly * lx                : 0.f;
    }

    float acc[COUTc];
#pragma unroll
    for (int o = 0; o < COUTc; ++o) acc[o] = 0.f;

    const float* xb = x + (size_t)b * Cc * HWp;

    for (int c = 0; c < Cc; ++c) {
        const float* xp = xb + c * HWp;
        float sv[9];
#pragma unroll
        for (int k = 0; k < 9; ++k)
            sv[k] = wgt[k][0] * xp[lin[k][0]] + wgt[k][1] * xp[lin[k][1]]
                  + wgt[k][2] * xp[lin[k][2]] + wgt[k][3] * xp[lin[k][3]];
        const float* wp = wT + c * 9 * 64;       // uniform address -> s_load
#pragma unroll
        for (int k = 0; k < 9; ++k) {
            float s = sv[k];
#pragma unroll
            for (int o = 0; o < COUTc; ++o)
                acc[o] += s * wp[k * 64 + o];
        }
    }

#pragma unroll
    for (int o = 0; o < COUTc; ++o)
        out[((size_t)b * COUTc + o) * HWp + pix] = acc[o] + bias[o];
}

// ---------------------------------------------------------------------------
extern "C" void kernel_launch(void* const* d_in, const int* in_sizes, int n_in,
                              void* d_out, int out_size, void* d_ws, size_t ws_size,
                              hipStream_t stream) {
    const float* x      = (const float*)d_in[0];
    const float* w_off  = (const float*)d_in[1];
    const float* b_off  = (const float*)d_in[2];
    const float* weight = (const float*)d_in[3];
    const float* bias   = (const float*)d_in[4];
    float* outp = (float*)d_out;
    float* ws   = (float*)d_ws;

    // 1) transpose weights into workspace
    prep_kernel<<<(64 * 576 + 255) / 256, 256, 0, stream>>>(weight, w_off, ws);

    // 2) offset conv -> ws offset region
    int npix = Bq * Hh * Ww;                     // 102400
    off_conv_kernel<<<npix / 64, 64, 0, stream>>>(x, b_off, ws, ws + OFF_OFS);

    // 3) fused bilinear-sample + matvec
    deform_kernel<<<npix / 64, 64, 0, stream>>>(x, bias, ws, outp);
}

// Round 2
// 284.886 us; speedup vs baseline: 1.6929x; 1.6929x over previous
//
#include <hip/hip_runtime.h>

// Problem constants
#define Bq   4
#define Cc   64
#define Hh   160
#define Ww   160
#define HWp  (Hh * Ww)          // 25600
#define COUTc 64

typedef __attribute__((ext_vector_type(8))) short bf16x8;
typedef __attribute__((ext_vector_type(4))) float f32x4;
typedef __attribute__((ext_vector_type(4))) int   int4v;

// ws layout (shorts):
//   wTb   [o][tap*64+c]   o<64  : 64*576 bf16
//   wToffb[oc][tap*64+c]  oc<32 : 32*576 bf16 (cols 18..31 zero)
#define WTB_SHORTS   (64 * 576)
#define WTOFF_SHORTS (32 * 576)

__device__ __forceinline__ short f2bf(float f) {
    union { float f; unsigned u; } v; v.f = f;
    unsigned r = v.u + 0x7fffu + ((v.u >> 16) & 1u);   // RNE
    return (short)(r >> 16);
}

// ---------------------------------------------------------------------------
// Prep: bf16 weight images, K reordered tap-major (k = tap*64 + c), stored
// column-major-in-k so B-fragments are contiguous 16B loads.
// ---------------------------------------------------------------------------
__global__ __launch_bounds__(256) void prep_kernel(const float* __restrict__ w,
                                                   const float* __restrict__ w_off,
                                                   short* __restrict__ ws) {
    int i = blockIdx.x * 256 + threadIdx.x;
    if (i < WTB_SHORTS) {
        int o = i / 576, rem = i - o * 576;
        int t = rem >> 6, c = rem & 63;
        ws[i] = f2bf(w[o * 576 + c * 9 + t]);
    }
    if (i < WTOFF_SHORTS) {
        int oc = i / 576, rem = i - oc * 576;
        int t = rem >> 6, c = rem & 63;
        float v = (oc < 18) ? w_off[oc * 576 + c * 9 + t] : 0.f;
        ws[WTB_SHORTS + i] = f2bf(v);
    }
}

// ---------------------------------------------------------------------------
// Fused: per wave, a 16-pixel tile (one row segment).
//  Phase 1: offset conv as MFMA GEMM (M=16 pix, N=32 (18 used), K=576)
//  Phase 2: bilinear lin/wgt tables (fp32) in LDS
//  Phase 3: main GEMM (M=16, N=64, K=576), A built from gathered samples
// ---------------------------------------------------------------------------
__global__ __launch_bounds__(256) void fused_kernel(const float* __restrict__ x,
                                                    const float* __restrict__ b_off,
                                                    const float* __restrict__ bias,
                                                    const short* __restrict__ ws,
                                                    float* __restrict__ out) {
    __shared__ float offbuf[4][16][20];   // [wave][pixel][offset-channel]
    __shared__ int4v linT[4][16][9];      // [wave][pixel][tap] 4 corner indices
    __shared__ f32x4 wgtT[4][16][9];      // [wave][pixel][tap] 4 corner weights

    int tid = threadIdx.x;
    int wid = tid >> 6;
    int l   = tid & 63;
    int lr  = l & 15;     // A-row / B-col lane index
    int lg  = l >> 4;     // k-chunk group 0..3

    int g        = blockIdx.x * 4 + wid;
    int pix_base = g * 16;
    int b   = pix_base / HWp;
    int rem = pix_base - b * HWp;
    int y   = rem / Ww;
    int x0  = rem - y * Ww;

    const float* xb     = x + (size_t)b * Cc * HWp;
    const short* wTb    = ws;
    const short* wToffb = ws + WTB_SHORTS;

    // ---------------- Phase 1: offset GEMM ----------------
    f32x4 accO0 = {0.f, 0.f, 0.f, 0.f};
    f32x4 accO1 = {0.f, 0.f, 0.f, 0.f};
    int xxb = x0 + lr - 1;
    for (int ty = 0; ty < 3; ++ty) {
        int yy = y - 1 + ty;
        if (yy < 0 || yy >= Hh) continue;          // wave-uniform
        for (int tx = 0; tx < 3; ++tx) {
            int tap = ty * 3 + tx;
            int xx  = xxb + tx;
            bool xok = (xx >= 0) && (xx < Ww);
            int xxc  = min(max(xx, 0), Ww - 1);
            int lin  = yy * Ww + xxc;
#pragma unroll
            for (int half = 0; half < 2; ++half) {
                int c0 = half * 32 + lg * 8;
                const float* xp = xb + (size_t)c0 * HWp + lin;
                bf16x8 af;
#pragma unroll
                for (int j = 0; j < 8; ++j) {
                    float v = xp[(size_t)j * HWp];
                    af[j] = xok ? f2bf(v) : (short)0;
                }
                int k0 = tap * 64 + half * 32 + lg * 8;
                bf16x8 bo0 = *(const bf16x8*)(wToffb + (size_t)lr * 576 + k0);
                bf16x8 bo1 = *(const bf16x8*)(wToffb + (size_t)(16 + lr) * 576 + k0);
                accO0 = __builtin_amdgcn_mfma_f32_16x16x32_bf16(af, bo0, accO0, 0, 0, 0);
                accO1 = __builtin_amdgcn_mfma_f32_16x16x32_bf16(af, bo1, accO1, 0, 0, 0);
            }
        }
    }
    // C layout: col = lr (= offset channel), row = lg*4+j (= pixel)
    {
        float bv0 = b_off[lr];
#pragma unroll
        for (int j = 0; j < 4; ++j) {
            int r = lg * 4 + j;
            offbuf[wid][r][lr] = accO0[j] + bv0;
        }
        if (lr < 2) {
            float bv1 = b_off[16 + lr];
#pragma unroll
            for (int j = 0; j < 4; ++j) {
                int r = lg * 4 + j;
                offbuf[wid][r][16 + lr] = accO1[j] + bv1;
            }
        }
    }
    __syncthreads();

    // ---------------- Phase 2: bilinear tables ----------------
    for (int i = l; i < 144; i += 64) {
        int r = i / 9, tap = i - r * 9;
        int ty = tap / 3, tx = tap - ty * 3;
        float dy = offbuf[wid][r][2 * tap];
        float dx = offbuf[wid][r][2 * tap + 1];
        float py = (float)(y - 1 + ty) + dy;
        float px = (float)(x0 + r - 1 + tx) + dx;
        float fy0 = floorf(py), fx0 = floorf(px);
        float ly = py - fy0, lx = px - fx0;
        int iy0 = (int)fy0, ix0 = (int)fx0;
        int iy1 = iy0 + 1,  ix1 = ix0 + 1;
        bool vy0 = (iy0 >= 0) && (iy0 < Hh);
        bool vy1 = (iy1 >= 0) && (iy1 < Hh);
        bool vx0 = (ix0 >= 0) && (ix0 < Ww);
        bool vx1 = (ix1 >= 0) && (ix1 < Ww);
        int cy0 = min(max(iy0, 0), Hh - 1), cy1 = min(max(iy1, 0), Hh - 1);
        int cx0 = min(max(ix0, 0), Ww - 1), cx1 = min(max(ix1, 0), Ww - 1);
        int4v li; f32x4 wg;
        li[0] = cy0 * Ww + cx0;  wg[0] = (vy0 && vx0) ? (1.f - ly) * (1.f - lx) : 0.f;
        li[1] = cy0 * Ww + cx1;  wg[1] = (vy0 && vx1) ? (1.f - ly) * lx         : 0.f;
        li[2] = cy1 * Ww + cx0;  wg[2] = (vy1 && vx0) ? ly * (1.f - lx)         : 0.f;
        li[3] = cy1 * Ww + cx1;  wg[3] = (vy1 && vx1) ? ly * lx                 : 0.f;
        linT[wid][r][tap] = li;
        wgtT[wid][r][tap] = wg;
    }
    __syncthreads();

    // ---------------- Phase 3: main GEMM ----------------
    f32x4 acc[4];
#pragma unroll
    for (int nt = 0; nt < 4; ++nt) acc[nt] = (f32x4){0.f, 0.f, 0.f, 0.f};

    for (int tap = 0; tap < 9; ++tap) {
        int4v li = linT[wid][lr][tap];
        f32x4 wg = wgtT[wid][lr][tap];
#pragma unroll
        for (int half = 0; half < 2; ++half) {
            int c0 = half * 32 + lg * 8;
            const float* xp = xb + (size_t)c0 * HWp;
            bf16x8 af;
#pragma unroll
            for (int j = 0; j < 8; ++j) {
                const float* p = xp + (size_t)j * HWp;
                float v = wg[0] * p[li[0]] + wg[1] * p[li[1]]
                        + wg[2] * p[li[2]] + wg[3] * p[li[3]];
                af[j] = f2bf(v);
            }
            int k0 = tap * 64 + half * 32 + lg * 8;
            const short* wb = wTb + (size_t)lr * 576 + k0;
            bf16x8 b0 = *(const bf16x8*)(wb);
            bf16x8 b1 = *(const bf16x8*)(wb +  9216);
            bf16x8 b2 = *(const bf16x8*)(wb + 18432);
            bf16x8 b3 = *(const bf16x8*)(wb + 27648);
            acc[0] = __builtin_amdgcn_mfma_f32_16x16x32_bf16(af, b0, acc[0], 0, 0, 0);
            acc[1] = __builtin_amdgcn_mfma_f32_16x16x32_bf16(af, b1, acc[1], 0, 0, 0);
            acc[2] = __builtin_amdgcn_mfma_f32_16x16x32_bf16(af, b2, acc[2], 0, 0, 0);
            acc[3] = __builtin_amdgcn_mfma_f32_16x16x32_bf16(af, b3, acc[3], 0, 0, 0);
        }
    }

    // ---------------- Epilogue ----------------
    float* ob = out + (size_t)b * COUTc * HWp + y * Ww + x0;
#pragma unroll
    for (int nt = 0; nt < 4; ++nt) {
        int o = nt * 16 + lr;
        float bv = bias[o];
#pragma unroll
        for (int j = 0; j < 4; ++j) {
            int r = lg * 4 + j;
            ob[(size_t)o * HWp + r] = acc[nt][j] + bv;
        }
    }
}

// ---------------------------------------------------------------------------
extern "C" void kernel_launch(void* const* d_in, const int* in_sizes, int n_in,
                              void* d_out, int out_size, void* d_ws, size_t ws_size,
                              hipStream_t stream) {
    const float* x      = (const float*)d_in[0];
    const float* w_off  = (const float*)d_in[1];
    const float* b_off  = (const float*)d_in[2];
    const float* weight = (const float*)d_in[3];
    const float* bias   = (const float*)d_in[4];
    float* outp = (float*)d_out;
    short* ws   = (short*)d_ws;

    prep_kernel<<<(WTB_SHORTS + 255) / 256, 256, 0, stream>>>(weight, w_off, ws);

    int nblocks = (Bq * HWp) / 64;   // 1600 workgroups x 4 waves x 16 pixels
    fused_kernel<<<nblocks, 256, 0, stream>>>(x, b_off, bias, ws, outp);
}

// Round 3
// 168.713 us; speedup vs baseline: 2.8587x; 1.6886x over previous
//
#include <hip/hip_runtime.h>
#include <hip/hip_bf16.h>

// Problem constants
#define Bq   4
#define Cc   64
#define Hh   160
#define Ww   160
#define HWp  (Hh * Ww)          // 25600
#define COUTc 64

typedef __attribute__((ext_vector_type(8))) short bf16x8;
typedef __attribute__((ext_vector_type(4))) float f32x4;
typedef __attribute__((ext_vector_type(4))) int   int4v;

// ws layout (shorts):
//   wTb   [o][tap*64+c]   o<64  : 64*576
//   wToffb[oc][tap*64+c]  oc<32 : 32*576 (cols 18..31 zero)
//   xcl   [b][y][x][c]          : 4*25600*64   (channels-last bf16 image)
#define WTB_SHORTS   (64 * 576)
#define WTOFF_SHORTS (32 * 576)
#define XCL_OFS      (WTB_SHORTS + WTOFF_SHORTS)
#define XCL_SHORTS   ((size_t)Bq * HWp * 64)

__device__ __forceinline__ short f2bf(float f) {
    union { float f; unsigned u; } v; v.f = f;
    unsigned r = v.u + 0x7fffu + ((v.u >> 16) & 1u);   // RNE
    return (short)(r >> 16);
}
__device__ __forceinline__ float bflo(unsigned u) {
    union { unsigned u; float f; } v; v.u = u << 16; return v.f;
}
__device__ __forceinline__ float bfhi(unsigned u) {
    union { unsigned u; float f; } v; v.u = u & 0xffff0000u; return v.f;
}
__device__ __forceinline__ unsigned pk2(float lo, float hi) {
    union { __hip_bfloat162 h; unsigned u; } v;
    v.h = __float22bfloat162_rn(float2{lo, hi});       // v_cvt_pk_bf16_f32
    return v.u;
}

// ---------------------------------------------------------------------------
// Prep: bf16 weight images, K tap-major (k = tap*64 + c)
// ---------------------------------------------------------------------------
__global__ __launch_bounds__(256) void prep_w(const float* __restrict__ w,
                                              const float* __restrict__ w_off,
                                              short* __restrict__ ws) {
    int i = blockIdx.x * 256 + threadIdx.x;
    if (i < WTB_SHORTS) {
        int o = i / 576, rem = i - o * 576;
        int t = rem >> 6, c = rem & 63;
        ws[i] = f2bf(w[o * 576 + c * 9 + t]);
    }
    if (i < WTOFF_SHORTS) {
        int oc = i / 576, rem = i - oc * 576;
        int t = rem >> 6, c = rem & 63;
        float v = (oc < 18) ? w_off[oc * 576 + c * 9 + t] : 0.f;
        ws[WTB_SHORTS + i] = f2bf(v);
    }
}

// ---------------------------------------------------------------------------
// Prep: channels-last bf16 image. One thread per pixel; reads coalesced
// (lane-adjacent pixels, per channel), writes 8x16B per thread.
// ---------------------------------------------------------------------------
__global__ __launch_bounds__(256) void prep_x(const float* __restrict__ x,
                                              short* __restrict__ xcl) {
    int g = blockIdx.x * 256 + threadIdx.x;     // 102400 threads
    int b = g / HWp, p = g - b * HWp;
    const float* xp = x + (size_t)b * Cc * HWp + p;
    short* op = xcl + (size_t)g * 64;
#pragma unroll
    for (int cg = 0; cg < 8; ++cg) {
        unsigned d[4];
#pragma unroll
        for (int dj = 0; dj < 4; ++dj) {
            float f0 = xp[(size_t)(cg * 8 + 2 * dj) * HWp];
            float f1 = xp[(size_t)(cg * 8 + 2 * dj + 1) * HWp];
            d[dj] = pk2(f0, f1);
        }
        *(int4v*)(op + cg * 8) = *(int4v*)d;
    }
}

// ---------------------------------------------------------------------------
// Fused, channels-last: per wave a 16-pixel row segment.
//  Phase 1: offset conv MFMA GEMM (A loaded straight from xcl)
//  Phase 2: bilinear tables (byte offsets into xcl)
//  Phase 3: main GEMM, A built from 16B corner loads + fp32 bilinear
// ---------------------------------------------------------------------------
__global__ __launch_bounds__(256) void fused_cl(const short* __restrict__ ws,
                                                const float* __restrict__ b_off,
                                                const float* __restrict__ bias,
                                                float* __restrict__ out) {
    __shared__ float offbuf[4][16][20];
    __shared__ int4v linT[4][16][9];    // byte offsets of 4 corners
    __shared__ f32x4 wgtT[4][16][9];

    int tid = threadIdx.x;
    int wid = tid >> 6;
    int l   = tid & 63;
    int lr  = l & 15;
    int lg  = l >> 4;

    // XCD-aware swizzle: nwg = 1600, 1600 % 8 == 0 -> bijective
    int bid = blockIdx.x;
    int g_blk = (bid & 7) * 200 + (bid >> 3);

    int gw       = g_blk * 4 + wid;
    int pix_base = gw * 16;
    int b   = pix_base / HWp;
    int rem = pix_base - b * HWp;
    int y   = rem / Ww;
    int x0  = rem - y * Ww;

    const short* wTb    = ws;
    const short* wToffb = ws + WTB_SHORTS;
    const char*  xclb   = (const char*)(ws + XCL_OFS) + (size_t)b * HWp * 128;

    int chan_byte = lg * 16;   // lg*8 channels * 2B

    // ---------------- Phase 1: offset GEMM ----------------
    f32x4 accO0 = {0.f, 0.f, 0.f, 0.f};
    f32x4 accO1 = {0.f, 0.f, 0.f, 0.f};
    for (int ty = 0; ty < 3; ++ty) {
        int yy = y - 1 + ty;
        if (yy < 0 || yy >= Hh) continue;           // wave-uniform
        for (int tx = 0; tx < 3; ++tx) {
            int tap = ty * 3 + tx;
            int xx  = x0 + lr - 1 + tx;
            bool xok = (xx >= 0) && (xx < Ww);
            int xxc  = min(max(xx, 0), Ww - 1);
            const char* pbase = xclb + (size_t)(yy * Ww + xxc) * 128 + chan_byte;
#pragma unroll
            for (int half = 0; half < 2; ++half) {
                bf16x8 af = *(const bf16x8*)(pbase + half * 64);
                if (!xok) {
#pragma unroll
                    for (int j = 0; j < 8; ++j) af[j] = 0;
                }
                int k0 = tap * 64 + half * 32 + lg * 8;
                bf16x8 bo0 = *(const bf16x8*)(wToffb + (size_t)lr * 576 + k0);
                bf16x8 bo1 = *(const bf16x8*)(wToffb + (size_t)(16 + lr) * 576 + k0);
                accO0 = __builtin_amdgcn_mfma_f32_16x16x32_bf16(af, bo0, accO0, 0, 0, 0);
                accO1 = __builtin_amdgcn_mfma_f32_16x16x32_bf16(af, bo1, accO1, 0, 0, 0);
            }
        }
    }
    {
        float bv0 = b_off[lr];
#pragma unroll
        for (int j = 0; j < 4; ++j)
            offbuf[wid][lg * 4 + j][lr] = accO0[j] + bv0;
        if (lr < 2) {
            float bv1 = b_off[16 + lr];
#pragma unroll
            for (int j = 0; j < 4; ++j)
                offbuf[wid][lg * 4 + j][16 + lr] = accO1[j] + bv1;
        }
    }
    __syncthreads();

    // ---------------- Phase 2: bilinear tables ----------------
    for (int i = l; i < 144; i += 64) {
        int r = i / 9, tap = i - r * 9;
        int ty = tap / 3, tx = tap - ty * 3;
        float dy = offbuf[wid][r][2 * tap];
        float dx = offbuf[wid][r][2 * tap + 1];
        float py = (float)(y - 1 + ty) + dy;
        float px = (float)(x0 + r - 1 + tx) + dx;
        float fy0 = floorf(py), fx0 = floorf(px);
        float ly = py - fy0, lx = px - fx0;
        int iy0 = (int)fy0, ix0 = (int)fx0;
        int iy1 = iy0 + 1,  ix1 = ix0 + 1;
        bool vy0 = (iy0 >= 0) && (iy0 < Hh);
        bool vy1 = (iy1 >= 0) && (iy1 < Hh);
        bool vx0 = (ix0 >= 0) && (ix0 < Ww);
        bool vx1 = (ix1 >= 0) && (ix1 < Ww);
        int cy0 = min(max(iy0, 0), Hh - 1), cy1 = min(max(iy1, 0), Hh - 1);
        int cx0 = min(max(ix0, 0), Ww - 1), cx1 = min(max(ix1, 0), Ww - 1);
        int4v li; f32x4 wg;
        li[0] = (cy0 * Ww + cx0) * 128;  wg[0] = (vy0 && vx0) ? (1.f - ly) * (1.f - lx) : 0.f;
        li[1] = (cy0 * Ww + cx1) * 128;  wg[1] = (vy0 && vx1) ? (1.f - ly) * lx         : 0.f;
        li[2] = (cy1 * Ww + cx0) * 128;  wg[2] = (vy1 && vx0) ? ly * (1.f - lx)         : 0.f;
        li[3] = (cy1 * Ww + cx1) * 128;  wg[3] = (vy1 && vx1) ? ly * lx                 : 0.f;
        linT[wid][r][tap] = li;
        wgtT[wid][r][tap] = wg;
    }
    __syncthreads();

    // ---------------- Phase 3: main GEMM ----------------
    f32x4 acc[4];
#pragma unroll
    for (int nt = 0; nt < 4; ++nt) acc[nt] = (f32x4){0.f, 0.f, 0.f, 0.f};

    for (int tap = 0; tap < 9; ++tap) {
        int4v li = linT[wid][lr][tap];
        f32x4 wg = wgtT[wid][lr][tap];
        const char* p0 = xclb + li[0] + chan_byte;
        const char* p1 = xclb + li[1] + chan_byte;
        const char* p2 = xclb + li[2] + chan_byte;
        const char* p3 = xclb + li[3] + chan_byte;
#pragma unroll
        for (int half = 0; half < 2; ++half) {
            bf16x8 c0 = *(const bf16x8*)(p0 + half * 64);
            bf16x8 c1 = *(const bf16x8*)(p1 + half * 64);
            bf16x8 c2 = *(const bf16x8*)(p2 + half * 64);
            bf16x8 c3 = *(const bf16x8*)(p3 + half * 64);
            union { bf16x8 v; unsigned u[4]; } U0, U1, U2, U3;
            U0.v = c0; U1.v = c1; U2.v = c2; U3.v = c3;
            unsigned ad[4];
#pragma unroll
            for (int d = 0; d < 4; ++d) {
                float s_lo = wg[0] * bflo(U0.u[d]) + wg[1] * bflo(U1.u[d])
                           + wg[2] * bflo(U2.u[d]) + wg[3] * bflo(U3.u[d]);
                float s_hi = wg[0] * bfhi(U0.u[d]) + wg[1] * bfhi(U1.u[d])
                           + wg[2] * bfhi(U2.u[d]) + wg[3] * bfhi(U3.u[d]);
                ad[d] = pk2(s_lo, s_hi);
            }
            bf16x8 af;
            {
                union { unsigned u[4]; bf16x8 v; } A;
                A.u[0] = ad[0]; A.u[1] = ad[1]; A.u[2] = ad[2]; A.u[3] = ad[3];
                af = A.v;
            }
            int k0 = tap * 64 + half * 32 + lg * 8;
            const short* wb = wTb + (size_t)lr * 576 + k0;
            bf16x8 b0 = *(const bf16x8*)(wb);
            bf16x8 b1 = *(const bf16x8*)(wb +  9216);
            bf16x8 b2 = *(const bf16x8*)(wb + 18432);
            bf16x8 b3 = *(const bf16x8*)(wb + 27648);
            acc[0] = __builtin_amdgcn_mfma_f32_16x16x32_bf16(af, b0, acc[0], 0, 0, 0);
            acc[1] = __builtin_amdgcn_mfma_f32_16x16x32_bf16(af, b1, acc[1], 0, 0, 0);
            acc[2] = __builtin_amdgcn_mfma_f32_16x16x32_bf16(af, b2, acc[2], 0, 0, 0);
            acc[3] = __builtin_amdgcn_mfma_f32_16x16x32_bf16(af, b3, acc[3], 0, 0, 0);
        }
    }

    // ---------------- Epilogue ----------------
    float* ob = out + (size_t)b * COUTc * HWp + y * Ww + x0;
#pragma unroll
    for (int nt = 0; nt < 4; ++nt) {
        int o = nt * 16 + lr;
        float bv = bias[o];
#pragma unroll
        for (int j = 0; j < 4; ++j)
            ob[(size_t)o * HWp + lg * 4 + j] = acc[nt][j] + bv;
    }
}

// ---------------------------------------------------------------------------
// Fallback (round-2 kernel, fp32-direct x) in case ws_size < 12.7 MB.
// ---------------------------------------------------------------------------
__global__ __launch_bounds__(256) void fused_fb(const float* __restrict__ x,
                                                const float* __restrict__ b_off,
                                                const float* __restrict__ bias,
                                                const short* __restrict__ ws,
                                                float* __restrict__ out) {
    __shared__ float offbuf[4][16][20];
    __shared__ int4v linT[4][16][9];
    __shared__ f32x4 wgtT[4][16][9];

    int tid = threadIdx.x, wid = tid >> 6, l = tid & 63, lr = l & 15, lg = l >> 4;
    int g = blockIdx.x * 4 + wid;
    int pix_base = g * 16;
    int b = pix_base / HWp, rem = pix_base - b * HWp;
    int y = rem / Ww, x0 = rem - y * Ww;

    const float* xb     = x + (size_t)b * Cc * HWp;
    const short* wTb    = ws;
    const short* wToffb = ws + WTB_SHORTS;

    f32x4 accO0 = {0.f,0.f,0.f,0.f}, accO1 = {0.f,0.f,0.f,0.f};
    int xxb = x0 + lr - 1;
    for (int ty = 0; ty < 3; ++ty) {
        int yy = y - 1 + ty;
        if (yy < 0 || yy >= Hh) continue;
        for (int tx = 0; tx < 3; ++tx) {
            int tap = ty * 3 + tx;
            int xx = xxb + tx;
            bool xok = (xx >= 0) && (xx < Ww);
            int xxc = min(max(xx, 0), Ww - 1);
            int lin = yy * Ww + xxc;
#pragma unroll
            for (int half = 0; half < 2; ++half) {
                int c0 = half * 32 + lg * 8;
                const float* xp = xb + (size_t)c0 * HWp + lin;
                bf16x8 af;
#pragma unroll
                for (int j = 0; j < 8; ++j) {
                    float v = xp[(size_t)j * HWp];
                    af[j] = xok ? f2bf(v) : (short)0;
                }
                int k0 = tap * 64 + half * 32 + lg * 8;
                bf16x8 bo0 = *(const bf16x8*)(wToffb + (size_t)lr * 576 + k0);
                bf16x8 bo1 = *(const bf16x8*)(wToffb + (size_t)(16 + lr) * 576 + k0);
                accO0 = __builtin_amdgcn_mfma_f32_16x16x32_bf16(af, bo0, accO0, 0, 0, 0);
                accO1 = __builtin_amdgcn_mfma_f32_16x16x32_bf16(af, bo1, accO1, 0, 0, 0);
            }
        }
    }
    {
        float bv0 = b_off[lr];
#pragma unroll
        for (int j = 0; j < 4; ++j) offbuf[wid][lg * 4 + j][lr] = accO0[j] + bv0;
        if (lr < 2) {
            float bv1 = b_off[16 + lr];
#pragma unroll
            for (int j = 0; j < 4; ++j) offbuf[wid][lg * 4 + j][16 + lr] = accO1[j] + bv1;
        }
    }
    __syncthreads();

    for (int i = l; i < 144; i += 64) {
        int r = i / 9, tap = i - r * 9;
        int ty = tap / 3, tx = tap - ty * 3;
        float dy = offbuf[wid][r][2 * tap];
        float dx = offbuf[wid][r][2 * tap + 1];
        float py = (float)(y - 1 + ty) + dy;
        float px = (float)(x0 + r - 1 + tx) + dx;
        float fy0 = floorf(py), fx0 = floorf(px);
        float ly = py - fy0, lx = px - fx0;
        int iy0 = (int)fy0, ix0 = (int)fx0;
        int iy1 = iy0 + 1, ix1 = ix0 + 1;
        bool vy0 = (iy0 >= 0) && (iy0 < Hh), vy1 = (iy1 >= 0) && (iy1 < Hh);
        bool vx0 = (ix0 >= 0) && (ix0 < Ww), vx1 = (ix1 >= 0) && (ix1 < Ww);
        int cy0 = min(max(iy0, 0), Hh - 1), cy1 = min(max(iy1, 0), Hh - 1);
        int cx0 = min(max(ix0, 0), Ww - 1), cx1 = min(max(ix1, 0), Ww - 1);
        int4v li; f32x4 wg;
        li[0] = cy0 * Ww + cx0; wg[0] = (vy0 && vx0) ? (1.f - ly) * (1.f - lx) : 0.f;
        li[1] = cy0 * Ww + cx1; wg[1] = (vy0 && vx1) ? (1.f - ly) * lx : 0.f;
        li[2] = cy1 * Ww + cx0; wg[2] = (vy1 && vx0) ? ly * (1.f - lx) : 0.f;
        li[3] = cy1 * Ww + cx1; wg[3] = (vy1 && vx1) ? ly * lx : 0.f;
        linT[wid][r][tap] = li;
        wgtT[wid][r][tap] = wg;
    }
    __syncthreads();

    f32x4 acc[4];
#pragma unroll
    for (int nt = 0; nt < 4; ++nt) acc[nt] = (f32x4){0.f,0.f,0.f,0.f};

    for (int tap = 0; tap < 9; ++tap) {
        int4v li = linT[wid][lr][tap];
        f32x4 wg = wgtT[wid][lr][tap];
#pragma unroll
        for (int half = 0; half < 2; ++half) {
            int c0 = half * 32 + lg * 8;
            const float* xp = xb + (size_t)c0 * HWp;
            bf16x8 af;
#pragma unroll
            for (int j = 0; j < 8; ++j) {
                const float* p = xp + (size_t)j * HWp;
                float v = wg[0] * p[li[0]] + wg[1] * p[li[1]]
                        + wg[2] * p[li[2]] + wg[3] * p[li[3]];
                af[j] = f2bf(v);
            }
            int k0 = tap * 64 + half * 32 + lg * 8;
            const short* wb = wTb + (size_t)lr * 576 + k0;
            bf16x8 b0 = *(const bf16x8*)(wb);
            bf16x8 b1 = *(const bf16x8*)(wb +  9216);
            bf16x8 b2 = *(const bf16x8*)(wb + 18432);
            bf16x8 b3 = *(const bf16x8*)(wb + 27648);
            acc[0] = __builtin_amdgcn_mfma_f32_16x16x32_bf16(af, b0, acc[0], 0, 0, 0);
            acc[1] = __builtin_amdgcn_mfma_f32_16x16x32_bf16(af, b1, acc[1], 0, 0, 0);
            acc[2] = __builtin_amdgcn_mfma_f32_16x16x32_bf16(af, b2, acc[2], 0, 0, 0);
            acc[3] = __builtin_amdgcn_mfma_f32_16x16x32_bf16(af, b3, acc[3], 0, 0, 0);
        }
    }

    float* ob = out + (size_t)b * COUTc * HWp + y * Ww + x0;
#pragma unroll
    for (int nt = 0; nt < 4; ++nt) {
        int o = nt * 16 + lr;
        float bv = bias[o];
#pragma unroll
        for (int j = 0; j < 4; ++j)
            ob[(size_t)o * HWp + lg * 4 + j] = acc[nt][j] + bv;
    }
}

// ---------------------------------------------------------------------------
extern "C" void kernel_launch(void* const* d_in, const int* in_sizes, int n_in,
                              void* d_out, int out_size, void* d_ws, size_t ws_size,
                              hipStream_t stream) {
    const float* x      = (const float*)d_in[0];
    const float* w_off  = (const float*)d_in[1];
    const float* b_off  = (const float*)d_in[2];
    const float* weight = (const float*)d_in[3];
    const float* bias   = (const float*)d_in[4];
    float* outp = (float*)d_out;
    short* ws   = (short*)d_ws;

    prep_w<<<(WTB_SHORTS + 255) / 256, 256, 0, stream>>>(weight, w_off, ws);

    size_t need_bytes = (size_t)(XCL_OFS + XCL_SHORTS) * 2;   // ~12.7 MB
    int nblocks = (Bq * HWp) / 64;                            // 1600

    if (ws_size >= need_bytes) {
        prep_x<<<(Bq * HWp) / 256, 256, 0, stream>>>(x, ws + XCL_OFS);
        fused_cl<<<nblocks, 256, 0, stream>>>(ws, b_off, bias, outp);
    } else {
        fused_fb<<<nblocks, 256, 0, stream>>>(x, b_off, bias, ws, outp);
    }
}

// Round 4
// 164.072 us; speedup vs baseline: 2.9395x; 1.0283x over previous
//
#include <hip/hip_runtime.h>
#include <hip/hip_bf16.h>

// Problem constants
#define Bq   4
#define Cc   64
#define Hh   160
#define Ww   160
#define HWp  (Hh * Ww)          // 25600
#define COUTc 64

typedef __attribute__((ext_vector_type(8))) short bf16x8;
typedef __attribute__((ext_vector_type(4))) float f32x4;
typedef __attribute__((ext_vector_type(4))) int   int4v;

// ws layout (shorts):
//   wTb   [o][tap*64+c]   o<64  : 64*576
//   wToffb[oc][tap*64+c]  oc<32 : 32*576 (cols 18..31 zero)
//   xcl   [b][y][x][c]          : 4*25600*64   (channels-last bf16 image)
#define WTB_SHORTS   (64 * 576)
#define WTOFF_SHORTS (32 * 576)
#define XCL_OFS      (WTB_SHORTS + WTOFF_SHORTS)
#define XCL_SHORTS   ((size_t)Bq * HWp * 64)

__device__ __forceinline__ short f2bf(float f) {
    union { float f; unsigned u; } v; v.f = f;
    unsigned r = v.u + 0x7fffu + ((v.u >> 16) & 1u);   // RNE
    return (short)(r >> 16);
}
__device__ __forceinline__ float bflo(unsigned u) {
    union { unsigned u; float f; } v; v.u = u << 16; return v.f;
}
__device__ __forceinline__ float bfhi(unsigned u) {
    union { unsigned u; float f; } v; v.u = u & 0xffff0000u; return v.f;
}
__device__ __forceinline__ unsigned pk2(float lo, float hi) {
    union { __hip_bfloat162 h; unsigned u; } v;
    v.h = __float22bfloat162_rn(float2{lo, hi});       // v_cvt_pk_bf16_f32
    return v.u;
}

// ---------------------------------------------------------------------------
// Merged prep: blocks [0,400) build channels-last bf16 image, blocks [400,544)
// build the two bf16 weight images (K tap-major, k = tap*64 + c).
// ---------------------------------------------------------------------------
__global__ __launch_bounds__(256) void prep_all(const float* __restrict__ x,
                                                const float* __restrict__ w,
                                                const float* __restrict__ w_off,
                                                short* __restrict__ ws) {
    int blk = blockIdx.x;
    if (blk < 400) {
        int g = blk * 256 + threadIdx.x;     // pixel id
        int b = g / HWp, p = g - b * HWp;
        const float* xp = x + (size_t)b * Cc * HWp + p;
        short* op = ws + XCL_OFS + (size_t)g * 64;
#pragma unroll
        for (int cg = 0; cg < 8; ++cg) {
            unsigned d[4];
#pragma unroll
            for (int dj = 0; dj < 4; ++dj) {
                float f0 = xp[(size_t)(cg * 8 + 2 * dj) * HWp];
                float f1 = xp[(size_t)(cg * 8 + 2 * dj + 1) * HWp];
                d[dj] = pk2(f0, f1);
            }
            *(int4v*)(op + cg * 8) = *(int4v*)d;
        }
    } else {
        int i = (blk - 400) * 256 + threadIdx.x;
        if (i < WTB_SHORTS) {
            int o = i / 576, rem = i - o * 576;
            int t = rem >> 6, c = rem & 63;
            ws[i] = f2bf(w[o * 576 + c * 9 + t]);
        }
        if (i < WTOFF_SHORTS) {
            int oc = i / 576, rem = i - oc * 576;
            int t = rem >> 6, c = rem & 63;
            float v = (oc < 18) ? w_off[oc * 576 + c * 9 + t] : 0.f;
            ws[WTB_SHORTS + i] = f2bf(v);
        }
    }
}

// ---------------------------------------------------------------------------
// Fused kernel, software-pipelined gathers.
// ---------------------------------------------------------------------------
__global__ __launch_bounds__(256, 4) void fused_cl(const short* __restrict__ ws,
                                                   const float* __restrict__ b_off,
                                                   const float* __restrict__ bias,
                                                   float* __restrict__ out) {
    __shared__ float offbuf[4][16][20];
    __shared__ int4v linT[4][16][9];    // byte offsets of 4 corners
    __shared__ f32x4 wgtT[4][16][9];

    int tid = threadIdx.x;
    int wid = tid >> 6;
    int l   = tid & 63;
    int lr  = l & 15;
    int lg  = l >> 4;

    // XCD-aware swizzle: nwg = 1600, 1600 % 8 == 0 -> bijective
    int bid = blockIdx.x;
    int g_blk = (bid & 7) * 200 + (bid >> 3);

    int gw       = g_blk * 4 + wid;
    int pix_base = gw * 16;
    int b   = pix_base / HWp;
    int rem = pix_base - b * HWp;
    int y   = rem / Ww;
    int x0  = rem - y * Ww;

    const short* wTb    = ws;
    const short* wToffb = ws + WTB_SHORTS;
    const char*  xclb   = (const char*)(ws + XCL_OFS) + (size_t)b * HWp * 128;

    int chan_byte = lg * 16;   // lg*8 channels * 2B

    // ---------------- Phase 1: offset GEMM (pipelined, mask-based) --------
    int poff[9];
    unsigned okb = 0;
#pragma unroll
    for (int ty = 0; ty < 3; ++ty) {
#pragma unroll
        for (int tx = 0; tx < 3; ++tx) {
            int t  = ty * 3 + tx;
            int yy = y - 1 + ty;
            int vy = (yy >= 0) && (yy < Hh);
            int yc = min(max(yy, 0), Hh - 1);
            int xx = x0 + lr - 1 + tx;
            int vx = (xx >= 0) && (xx < Ww);
            int xc = min(max(xx, 0), Ww - 1);
            poff[t] = (yc * Ww + xc) * 128;
            okb |= (unsigned)(vy && vx) << t;
        }
    }

    f32x4 accO0 = {0.f, 0.f, 0.f, 0.f};
    f32x4 accO1 = {0.f, 0.f, 0.f, 0.f};
    {
        bf16x8 p1[2][2];
        {
            const char* q = xclb + poff[0] + chan_byte;
            p1[0][0] = *(const bf16x8*)(q);
            p1[0][1] = *(const bf16x8*)(q + 64);
        }
#pragma unroll
        for (int t = 0; t < 9; ++t) {
            if (t < 8) {
                const char* q = xclb + poff[t + 1] + chan_byte;
                p1[(t + 1) & 1][0] = *(const bf16x8*)(q);
                p1[(t + 1) & 1][1] = *(const bf16x8*)(q + 64);
            }
            bool ok = (okb >> t) & 1u;
#pragma unroll
            for (int h = 0; h < 2; ++h) {
                bf16x8 af = p1[t & 1][h];
#pragma unroll
                for (int j = 0; j < 8; ++j)
                    af[j] = ok ? af[j] : (short)0;
                int k0 = t * 64 + h * 32 + lg * 8;
                bf16x8 bo0 = *(const bf16x8*)(wToffb + (size_t)lr * 576 + k0);
                bf16x8 bo1 = *(const bf16x8*)(wToffb + (size_t)(16 + lr) * 576 + k0);
                accO0 = __builtin_amdgcn_mfma_f32_16x16x32_bf16(af, bo0, accO0, 0, 0, 0);
                accO1 = __builtin_amdgcn_mfma_f32_16x16x32_bf16(af, bo1, accO1, 0, 0, 0);
            }
        }
    }
    {
        float bv0 = b_off[lr];
#pragma unroll
        for (int j = 0; j < 4; ++j)
            offbuf[wid][lg * 4 + j][lr] = accO0[j] + bv0;
        if (lr < 2) {
            float bv1 = b_off[16 + lr];
#pragma unroll
            for (int j = 0; j < 4; ++j)
                offbuf[wid][lg * 4 + j][16 + lr] = accO1[j] + bv1;
        }
    }
    __syncthreads();

    // ---------------- Phase 2: bilinear tables ----------------
    for (int i = l; i < 144; i += 64) {
        int r = i / 9, tap = i - r * 9;
        int ty = tap / 3, tx = tap - ty * 3;
        float dy = offbuf[wid][r][2 * tap];
        float dx = offbuf[wid][r][2 * tap + 1];
        float py = (float)(y - 1 + ty) + dy;
        float px = (float)(x0 + r - 1 + tx) + dx;
        float fy0 = floorf(py), fx0 = floorf(px);
        float ly = py - fy0, lx = px - fx0;
        int iy0 = (int)fy0, ix0 = (int)fx0;
        int iy1 = iy0 + 1,  ix1 = ix0 + 1;
        bool vy0 = (iy0 >= 0) && (iy0 < Hh);
        bool vy1 = (iy1 >= 0) && (iy1 < Hh);
        bool vx0 = (ix0 >= 0) && (ix0 < Ww);
        bool vx1 = (ix1 >= 0) && (ix1 < Ww);
        int cy0 = min(max(iy0, 0), Hh - 1), cy1 = min(max(iy1, 0), Hh - 1);
        int cx0 = min(max(ix0, 0), Ww - 1), cx1 = min(max(ix1, 0), Ww - 1);
        int4v li; f32x4 wg;
        li[0] = (cy0 * Ww + cx0) * 128;  wg[0] = (vy0 && vx0) ? (1.f - ly) * (1.f - lx) : 0.f;
        li[1] = (cy0 * Ww + cx1) * 128;  wg[1] = (vy0 && vx1) ? (1.f - ly) * lx         : 0.f;
        li[2] = (cy1 * Ww + cx0) * 128;  wg[2] = (vy1 && vx0) ? ly * (1.f - lx)         : 0.f;
        li[3] = (cy1 * Ww + cx1) * 128;  wg[3] = (vy1 && vx1) ? ly * lx                 : 0.f;
        linT[wid][r][tap] = li;
        wgtT[wid][r][tap] = wg;
    }
    __syncthreads();

    // ---------------- Phase 3: main GEMM (2-deep tap pipeline) ------------
    f32x4 acc[4];
#pragma unroll
    for (int nt = 0; nt < 4; ++nt) acc[nt] = (f32x4){0.f, 0.f, 0.f, 0.f};

#define LOADC(DST, LI) do {                                          \
        const char* q0 = xclb + (LI)[0] + chan_byte;                 \
        const char* q1 = xclb + (LI)[1] + chan_byte;                 \
        const char* q2 = xclb + (LI)[2] + chan_byte;                 \
        const char* q3 = xclb + (LI)[3] + chan_byte;                 \
        (DST)[0] = *(const bf16x8*)(q0); (DST)[1] = *(const bf16x8*)(q0 + 64); \
        (DST)[2] = *(const bf16x8*)(q1); (DST)[3] = *(const bf16x8*)(q1 + 64); \
        (DST)[4] = *(const bf16x8*)(q2); (DST)[5] = *(const bf16x8*)(q2 + 64); \
        (DST)[6] = *(const bf16x8*)(q3); (DST)[7] = *(const bf16x8*)(q3 + 64); \
    } while (0)

    {
        bf16x8 stg[2][8];
        {
            int4v li0 = linT[wid][lr][0];
            LOADC(stg[0], li0);
        }
#pragma unroll
        for (int tap = 0; tap < 9; ++tap) {
            if (tap < 8) {
                int4v lin2 = linT[wid][lr][tap + 1];
                LOADC(stg[(tap + 1) & 1], lin2);
            }
            f32x4 wg = wgtT[wid][lr][tap];
            const short* wb = wTb + (size_t)lr * 576 + tap * 64 + lg * 8;
#pragma unroll
            for (int h = 0; h < 2; ++h) {
                union { bf16x8 v; unsigned u[4]; } C0, C1, C2, C3;
                C0.v = stg[tap & 1][0 + h];
                C1.v = stg[tap & 1][2 + h];
                C2.v = stg[tap & 1][4 + h];
                C3.v = stg[tap & 1][6 + h];
                unsigned ad[4];
#pragma unroll
                for (int d = 0; d < 4; ++d) {
                    float slo = wg[0] * bflo(C0.u[d]) + wg[1] * bflo(C1.u[d])
                              + wg[2] * bflo(C2.u[d]) + wg[3] * bflo(C3.u[d]);
                    float shi = wg[0] * bfhi(C0.u[d]) + wg[1] * bfhi(C1.u[d])
                              + wg[2] * bfhi(C2.u[d]) + wg[3] * bfhi(C3.u[d]);
                    ad[d] = pk2(slo, shi);
                }
                bf16x8 af;
                {
                    union { unsigned u[4]; bf16x8 v; } A;
                    A.u[0] = ad[0]; A.u[1] = ad[1]; A.u[2] = ad[2]; A.u[3] = ad[3];
                    af = A.v;
                }
                const short* wbh = wb + h * 32;
                bf16x8 b0 = *(const bf16x8*)(wbh);
                bf16x8 b1 = *(const bf16x8*)(wbh +  9216);
                bf16x8 b2 = *(const bf16x8*)(wbh + 18432);
                bf16x8 b3 = *(const bf16x8*)(wbh + 27648);
                acc[0] = __builtin_amdgcn_mfma_f32_16x16x32_bf16(af, b0, acc[0], 0, 0, 0);
                acc[1] = __builtin_amdgcn_mfma_f32_16x16x32_bf16(af, b1, acc[1], 0, 0, 0);
                acc[2] = __builtin_amdgcn_mfma_f32_16x16x32_bf16(af, b2, acc[2], 0, 0, 0);
                acc[3] = __builtin_amdgcn_mfma_f32_16x16x32_bf16(af, b3, acc[3], 0, 0, 0);
            }
        }
    }
#undef LOADC

    // ---------------- Epilogue ----------------
    float* ob = out + (size_t)b * COUTc * HWp + y * Ww + x0;
#pragma unroll
    for (int nt = 0; nt < 4; ++nt) {
        int o = nt * 16 + lr;
        float bv = bias[o];
#pragma unroll
        for (int j = 0; j < 4; ++j)
            ob[(size_t)o * HWp + lg * 4 + j] = acc[nt][j] + bv;
    }
}

// ---------------------------------------------------------------------------
extern "C" void kernel_launch(void* const* d_in, const int* in_sizes, int n_in,
                              void* d_out, int out_size, void* d_ws, size_t ws_size,
                              hipStream_t stream) {
    const float* x      = (const float*)d_in[0];
    const float* w_off  = (const float*)d_in[1];
    const float* b_off  = (const float*)d_in[2];
    const float* weight = (const float*)d_in[3];
    const float* bias   = (const float*)d_in[4];
    float* outp = (float*)d_out;
    short* ws   = (short*)d_ws;

    // 400 blocks for xcl + 144 blocks for weight images
    prep_all<<<544, 256, 0, stream>>>(x, weight, w_off, ws);

    int nblocks = (Bq * HWp) / 64;   // 1600 workgroups x 4 waves x 16 pixels
    fused_cl<<<nblocks, 256, 0, stream>>>(ws, b_off, bias, outp);
}

// Round 5
// 134.809 us; speedup vs baseline: 3.5776x; 1.2171x over previous
//
#include <hip/hip_runtime.h>
#include <hip/hip_bf16.h>

// Problem constants
#define Bq   4
#define Cc   64
#define Hh   160
#define Ww   160
#define HWp  (Hh * Ww)          // 25600
#define COUTc 64

typedef __attribute__((ext_vector_type(8))) short bf16x8;
typedef __attribute__((ext_vector_type(4))) float f32x4;
typedef __attribute__((ext_vector_type(4))) int   int4v;

// ws layout (shorts):
//   wTb   [o][tap*64+c]   o<64  : 64*576
//   wToffb[oc][tap*64+c]  oc<32 : 32*576 (cols 18..31 zero)
//   xcl   [b][y][x][c]          : 4*25600*64   (channels-last bf16 image)
#define WTB_SHORTS   (64 * 576)
#define WTOFF_SHORTS (32 * 576)
#define XCL_OFS      (WTB_SHORTS + WTOFF_SHORTS)
#define XCL_SHORTS   ((size_t)Bq * HWp * 64)

__device__ __forceinline__ short f2bf(float f) {
    union { float f; unsigned u; } v; v.f = f;
    unsigned r = v.u + 0x7fffu + ((v.u >> 16) & 1u);   // RNE
    return (short)(r >> 16);
}
__device__ __forceinline__ float bflo(unsigned u) {
    union { unsigned u; float f; } v; v.u = u << 16; return v.f;
}
__device__ __forceinline__ float bfhi(unsigned u) {
    union { unsigned u; float f; } v; v.u = u & 0xffff0000u; return v.f;
}
__device__ __forceinline__ unsigned pk2(float lo, float hi) {
    union { __hip_bfloat162 h; unsigned u; } v;
    v.h = __float22bfloat162_rn(float2{lo, hi});       // v_cvt_pk_bf16_f32
    return v.u;
}

// ---------------------------------------------------------------------------
// Merged prep: blocks [0,400) build channels-last bf16 image, blocks [400,544)
// build the two bf16 weight images (K tap-major, k = tap*64 + c).
// ---------------------------------------------------------------------------
__global__ __launch_bounds__(256) void prep_all(const float* __restrict__ x,
                                                const float* __restrict__ w,
                                                const float* __restrict__ w_off,
                                                short* __restrict__ ws) {
    int blk = blockIdx.x;
    if (blk < 400) {
        int g = blk * 256 + threadIdx.x;     // pixel id
        int b = g / HWp, p = g - b * HWp;
        const float* xp = x + (size_t)b * Cc * HWp + p;
        short* op = ws + XCL_OFS + (size_t)g * 64;
#pragma unroll
        for (int cg = 0; cg < 8; ++cg) {
            unsigned d[4];
#pragma unroll
            for (int dj = 0; dj < 4; ++dj) {
                float f0 = xp[(size_t)(cg * 8 + 2 * dj) * HWp];
                float f1 = xp[(size_t)(cg * 8 + 2 * dj + 1) * HWp];
                d[dj] = pk2(f0, f1);
            }
            *(int4v*)(op + cg * 8) = *(int4v*)d;
        }
    } else {
        int i = (blk - 400) * 256 + threadIdx.x;
        if (i < WTB_SHORTS) {
            int o = i / 576, rem = i - o * 576;
            int t = rem >> 6, c = rem & 63;
            ws[i] = f2bf(w[o * 576 + c * 9 + t]);
        }
        if (i < WTOFF_SHORTS) {
            int oc = i / 576, rem = i - oc * 576;
            int t = rem >> 6, c = rem & 63;
            float v = (oc < 18) ? w_off[oc * 576 + c * 9 + t] : 0.f;
            ws[WTB_SHORTS + i] = f2bf(v);
        }
    }
}

// ---------------------------------------------------------------------------
// Fused kernel: 32-pixel tile per block; gather phase decoupled from GEMM
// via an LDS im2col tile so gathers are massively parallel & independent.
// ---------------------------------------------------------------------------
__global__ __launch_bounds__(256, 3) void fused_cl(const short* __restrict__ ws,
                                                   const float* __restrict__ b_off,
                                                   const float* __restrict__ bias,
                                                   float* __restrict__ out) {
    __shared__ short sm[9][32][72];     // sampled im2col, padded row (144 B)
    __shared__ float offbuf[32][20];
    __shared__ int4v linT[32][9];       // byte offsets of 4 corners
    __shared__ f32x4 wgtT[32][9];

    int tid = threadIdx.x;
    int wid = tid >> 6;
    int l   = tid & 63;
    int lr  = l & 15;
    int lg  = l >> 4;
    int mhalf = wid >> 1;      // pixel half: 0 -> px 0-15, 1 -> px 16-31
    int nhalf = wid & 1;       // col half (offset conv: oc, main: outch)

    // XCD-aware swizzle: nwg = 3200, 3200 % 8 == 0 -> bijective
    int bid = blockIdx.x;
    int g_blk = (bid & 7) * 400 + (bid >> 3);

    int pix_base = g_blk * 32;
    int b   = pix_base / HWp;
    int rem = pix_base - b * HWp;
    int y   = rem / Ww;
    int x0  = rem - y * Ww;            // multiple of 32, row-aligned

    const short* wTb    = ws;
    const short* wToffb = ws + WTB_SHORTS;
    const char*  xclb   = (const char*)(ws + XCL_OFS) + (size_t)b * HWp * 128;

    // ---------------- Phase 1: offset GEMM (1 wave = 1 quadrant) ----------
    {
        int px_t  = mhalf * 16 + lr;           // pixel within tile
        int xpix  = x0 + px_t;
        int poff[9];
        unsigned okb = 0;
#pragma unroll
        for (int ty = 0; ty < 3; ++ty) {
#pragma unroll
            for (int tx = 0; tx < 3; ++tx) {
                int t  = ty * 3 + tx;
                int yy = y - 1 + ty;
                int vy = (yy >= 0) && (yy < Hh);
                int yc = min(max(yy, 0), Hh - 1);
                int xx = xpix - 1 + tx;
                int vx = (xx >= 0) && (xx < Ww);
                int xc = min(max(xx, 0), Ww - 1);
                poff[t] = (yc * Ww + xc) * 128;
                okb |= (unsigned)(vy && vx) << t;
            }
        }

        f32x4 accO = {0.f, 0.f, 0.f, 0.f};
        int oc_row = nhalf * 16 + lr;          // B row (offset channel)
        const short* wor = wToffb + (size_t)oc_row * 576;
#pragma unroll
        for (int t = 0; t < 9; ++t) {
            const char* q = xclb + poff[t] + lg * 16;
            bool ok = (okb >> t) & 1u;
#pragma unroll
            for (int h = 0; h < 2; ++h) {
                bf16x8 af = *(const bf16x8*)(q + h * 64);
#pragma unroll
                for (int j = 0; j < 8; ++j)
                    af[j] = ok ? af[j] : (short)0;
                bf16x8 bo = *(const bf16x8*)(wor + t * 64 + h * 32 + lg * 8);
                accO = __builtin_amdgcn_mfma_f32_16x16x32_bf16(af, bo, accO, 0, 0, 0);
            }
        }
        if (oc_row < 18) {
            float bv = b_off[oc_row];
#pragma unroll
            for (int j = 0; j < 4; ++j)
                offbuf[mhalf * 16 + lg * 4 + j][oc_row] = accO[j] + bv;
        }
    }
    __syncthreads();

    // ---------------- Phase 2: bilinear tables ----------------
    for (int i = tid; i < 288; i += 256) {
        int r = i / 9, tap = i - r * 9;
        int ty = tap / 3, tx = tap - ty * 3;
        float dy = offbuf[r][2 * tap];
        float dx = offbuf[r][2 * tap + 1];
        float py = (float)(y - 1 + ty) + dy;
        float px = (float)(x0 + r - 1 + tx) + dx;
        float fy0 = floorf(py), fx0 = floorf(px);
        float ly = py - fy0, lx = px - fx0;
        int iy0 = (int)fy0, ix0 = (int)fx0;
        int iy1 = iy0 + 1,  ix1 = ix0 + 1;
        bool vy0 = (iy0 >= 0) && (iy0 < Hh);
        bool vy1 = (iy1 >= 0) && (iy1 < Hh);
        bool vx0 = (ix0 >= 0) && (ix0 < Ww);
        bool vx1 = (ix1 >= 0) && (ix1 < Ww);
        int cy0 = min(max(iy0, 0), Hh - 1), cy1 = min(max(iy1, 0), Hh - 1);
        int cx0 = min(max(ix0, 0), Ww - 1), cx1 = min(max(ix1, 0), Ww - 1);
        int4v li; f32x4 wg;
        li[0] = (cy0 * Ww + cx0) * 128;  wg[0] = (vy0 && vx0) ? (1.f - ly) * (1.f - lx) : 0.f;
        li[1] = (cy0 * Ww + cx1) * 128;  wg[1] = (vy0 && vx1) ? (1.f - ly) * lx         : 0.f;
        li[2] = (cy1 * Ww + cx0) * 128;  wg[2] = (vy1 && vx0) ? ly * (1.f - lx)         : 0.f;
        li[3] = (cy1 * Ww + cx1) * 128;  wg[3] = (vy1 && vx1) ? ly * lx                 : 0.f;
        linT[r][tap] = li;
        wgtT[r][tap] = wg;
    }
    __syncthreads();

    // ---------------- Phase 3a: cooperative sample build ------------------
    // unit(tap, px, cg): 4 independent corner loads + bilinear + ds_write.
    // 9 units per thread, all independent -> loads batch freely.
    {
        int px = tid >> 3;          // 0..31
        int cg = tid & 7;           // channel group (8 ch = 16 B)
        int cb = cg * 16;
#pragma unroll
        for (int tap = 0; tap < 9; ++tap) {
            int4v li = linT[px][tap];
            f32x4 wg = wgtT[px][tap];
            bf16x8 c0 = *(const bf16x8*)(xclb + li[0] + cb);
            bf16x8 c1 = *(const bf16x8*)(xclb + li[1] + cb);
            bf16x8 c2 = *(const bf16x8*)(xclb + li[2] + cb);
            bf16x8 c3 = *(const bf16x8*)(xclb + li[3] + cb);
            union { bf16x8 v; unsigned u[4]; } U0, U1, U2, U3;
            U0.v = c0; U1.v = c1; U2.v = c2; U3.v = c3;
            union { unsigned u[4]; bf16x8 v; } A;
#pragma unroll
            for (int d = 0; d < 4; ++d) {
                float slo = wg[0] * bflo(U0.u[d]) + wg[1] * bflo(U1.u[d])
                          + wg[2] * bflo(U2.u[d]) + wg[3] * bflo(U3.u[d]);
                float shi = wg[0] * bfhi(U0.u[d]) + wg[1] * bfhi(U1.u[d])
                          + wg[2] * bfhi(U2.u[d]) + wg[3] * bfhi(U3.u[d]);
                A.u[d] = pk2(slo, shi);
            }
            *(bf16x8*)(&sm[tap][px][cg * 8]) = A.v;
        }
    }
    __syncthreads();

    // ---------------- Phase 3b: main GEMM from LDS ------------------------
    // wave(mhalf,nhalf): A rows = px mhalf*16..+15, B cols = nhalf*32..+31.
    f32x4 acc[2];
    acc[0] = (f32x4){0.f, 0.f, 0.f, 0.f};
    acc[1] = (f32x4){0.f, 0.f, 0.f, 0.f};
    {
        int px_t = mhalf * 16 + lr;
        const short* wb0 = wTb + (size_t)(nhalf * 32 + lr) * 576;
        const short* wb1 = wTb + (size_t)(nhalf * 32 + 16 + lr) * 576;
#pragma unroll
        for (int tap = 0; tap < 9; ++tap) {
#pragma unroll
            for (int h = 0; h < 2; ++h) {
                bf16x8 af = *(const bf16x8*)(&sm[tap][px_t][h * 32 + lg * 8]);
                int k0 = tap * 64 + h * 32 + lg * 8;
                bf16x8 b0 = *(const bf16x8*)(wb0 + k0);
                bf16x8 b1 = *(const bf16x8*)(wb1 + k0);
                acc[0] = __builtin_amdgcn_mfma_f32_16x16x32_bf16(af, b0, acc[0], 0, 0, 0);
                acc[1] = __builtin_amdgcn_mfma_f32_16x16x32_bf16(af, b1, acc[1], 0, 0, 0);
            }
        }
    }

    // ---------------- Epilogue ----------------
    float* ob = out + (size_t)b * COUTc * HWp + y * Ww + x0;
#pragma unroll
    for (int nt = 0; nt < 2; ++nt) {
        int o = nhalf * 32 + nt * 16 + lr;
        float bv = bias[o];
#pragma unroll
        for (int j = 0; j < 4; ++j)
            ob[(size_t)o * HWp + mhalf * 16 + lg * 4 + j] = acc[nt][j] + bv;
    }
}

// ---------------------------------------------------------------------------
extern "C" void kernel_launch(void* const* d_in, const int* in_sizes, int n_in,
                              void* d_out, int out_size, void* d_ws, size_t ws_size,
                              hipStream_t stream) {
    const float* x      = (const float*)d_in[0];
    const float* w_off  = (const float*)d_in[1];
    const float* b_off  = (const float*)d_in[2];
    const float* weight = (const float*)d_in[3];
    const float* bias   = (const float*)d_in[4];
    float* outp = (float*)d_out;
    short* ws   = (short*)d_ws;

    // 400 blocks for xcl + 144 blocks for weight images
    prep_all<<<544, 256, 0, stream>>>(x, weight, w_off, ws);

    int nblocks = (Bq * HWp) / 32;   // 3200 workgroups, 32 pixels each
    fused_cl<<<nblocks, 256, 0, stream>>>(ws, b_off, bias, outp);
}

// Round 6
// 134.115 us; speedup vs baseline: 3.5961x; 1.0052x over previous
//
#include <hip/hip_runtime.h>
#include <hip/hip_bf16.h>

// Problem constants
#define Bq   4
#define Cc   64
#define Hh   160
#define Ww   160
#define HWp  (Hh * Ww)          // 25600
#define COUTc 64

typedef __attribute__((ext_vector_type(8))) short bf16x8;
typedef __attribute__((ext_vector_type(4))) float f32x4;
typedef __attribute__((ext_vector_type(2))) float f32x2;
typedef __attribute__((ext_vector_type(4))) int   int4v;

// ws layout (shorts):
//   wTb   [o][tap*64+c]   o<64  : 64*576
//   wToffb[oc][tap*64+c]  oc<32 : 32*576 (cols 18..31 zero)
//   xcl   [b][y][x][c]          : 4*25600*64   (channels-last bf16 image)
#define WTB_SHORTS   (64 * 576)
#define WTOFF_SHORTS (32 * 576)
#define XCL_OFS      (WTB_SHORTS + WTOFF_SHORTS)
#define XCL_SHORTS   ((size_t)Bq * HWp * 64)

__device__ __forceinline__ short f2bf(float f) {
    union { float f; unsigned u; } v; v.f = f;
    unsigned r = v.u + 0x7fffu + ((v.u >> 16) & 1u);   // RNE
    return (short)(r >> 16);
}
__device__ __forceinline__ float bflo(unsigned u) {
    union { unsigned u; float f; } v; v.u = u << 16; return v.f;
}
__device__ __forceinline__ float bfhi(unsigned u) {
    union { unsigned u; float f; } v; v.u = u & 0xffff0000u; return v.f;
}
__device__ __forceinline__ unsigned pk2(float lo, float hi) {
    union { __hip_bfloat162 h; unsigned u; } v;
    v.h = __float22bfloat162_rn(float2{lo, hi});       // v_cvt_pk_bf16_f32
    return v.u;
}

// ---------------------------------------------------------------------------
// Merged prep: blocks [0,400) build channels-last bf16 image, blocks [400,544)
// build the two bf16 weight images (K tap-major, k = tap*64 + c).
// ---------------------------------------------------------------------------
__global__ __launch_bounds__(256) void prep_all(const float* __restrict__ x,
                                                const float* __restrict__ w,
                                                const float* __restrict__ w_off,
                                                short* __restrict__ ws) {
    int blk = blockIdx.x;
    if (blk < 400) {
        int g = blk * 256 + threadIdx.x;     // pixel id
        int b = g / HWp, p = g - b * HWp;
        const float* xp = x + (size_t)b * Cc * HWp + p;
        short* op = ws + XCL_OFS + (size_t)g * 64;
#pragma unroll
        for (int cg = 0; cg < 8; ++cg) {
            unsigned d[4];
#pragma unroll
            for (int dj = 0; dj < 4; ++dj) {
                float f0 = xp[(size_t)(cg * 8 + 2 * dj) * HWp];
                float f1 = xp[(size_t)(cg * 8 + 2 * dj + 1) * HWp];
                d[dj] = pk2(f0, f1);
            }
            *(int4v*)(op + cg * 8) = *(int4v*)d;
        }
    } else {
        int i = (blk - 400) * 256 + threadIdx.x;
        if (i < WTB_SHORTS) {
            int o = i / 576, rem = i - o * 576;
            int t = rem >> 6, c = rem & 63;
            ws[i] = f2bf(w[o * 576 + c * 9 + t]);
        }
        if (i < WTOFF_SHORTS) {
            int oc = i / 576, rem = i - oc * 576;
            int t = rem >> 6, c = rem & 63;
            float v = (oc < 18) ? w_off[oc * 576 + c * 9 + t] : 0.f;
            ws[WTB_SHORTS + i] = f2bf(v);
        }
    }
}

// ---------------------------------------------------------------------------
// Sample NT taps (starting at T0) into sm; per-thread table recompute.
// thread = (px = tid>>3, cg = tid&7); cb = cg*16 byte channel offset.
// ---------------------------------------------------------------------------
template<int T0, int NT>
__device__ __forceinline__ void sample_taps(const char* __restrict__ xclb,
                                            const float (*__restrict__ offbuf)[20],
                                            short (*__restrict__ sm)[32][72],
                                            int px, int cb, int y, int xpix) {
#pragma unroll
    for (int ti = 0; ti < NT; ++ti) {
        const int t  = T0 + ti;
        const int ty = t / 3, tx = t % 3;
        f32x2 d2 = *(const f32x2*)&offbuf[px][2 * t];
        float py  = (float)(y - 1 + ty) + d2[0];
        float pxf = (float)(xpix - 1 + tx) + d2[1];
        float fy = floorf(py), fx = floorf(pxf);
        float ly = py - fy, lx = pxf - fx;
        int iy0 = (int)fy, ix0 = (int)fx;
        int iy1 = iy0 + 1, ix1 = ix0 + 1;
        bool vy0 = (iy0 >= 0) && (iy0 < Hh);
        bool vy1 = (iy1 >= 0) && (iy1 < Hh);
        bool vx0 = (ix0 >= 0) && (ix0 < Ww);
        bool vx1 = (ix1 >= 0) && (ix1 < Ww);
        int cy0 = min(max(iy0, 0), Hh - 1), cy1 = min(max(iy1, 0), Hh - 1);
        int cx0 = min(max(ix0, 0), Ww - 1), cx1 = min(max(ix1, 0), Ww - 1);
        float w00 = (vy0 && vx0) ? (1.f - ly) * (1.f - lx) : 0.f;
        float w01 = (vy0 && vx1) ? (1.f - ly) * lx         : 0.f;
        float w10 = (vy1 && vx0) ? ly * (1.f - lx)         : 0.f;
        float w11 = (vy1 && vx1) ? ly * lx                 : 0.f;

        bf16x8 c00 = *(const bf16x8*)(xclb + (cy0 * Ww + cx0) * 128 + cb);
        bf16x8 c01 = *(const bf16x8*)(xclb + (cy0 * Ww + cx1) * 128 + cb);
        bf16x8 c10 = *(const bf16x8*)(xclb + (cy1 * Ww + cx0) * 128 + cb);
        bf16x8 c11 = *(const bf16x8*)(xclb + (cy1 * Ww + cx1) * 128 + cb);

        union { bf16x8 v; unsigned u[4]; } U0, U1, U2, U3;
        U0.v = c00; U1.v = c01; U2.v = c10; U3.v = c11;
        union { unsigned u[4]; bf16x8 v; } A;
#pragma unroll
        for (int d = 0; d < 4; ++d) {
            f32x2 v0 = {bflo(U0.u[d]), bfhi(U0.u[d])};
            f32x2 v1 = {bflo(U1.u[d]), bfhi(U1.u[d])};
            f32x2 v2 = {bflo(U2.u[d]), bfhi(U2.u[d])};
            f32x2 v3 = {bflo(U3.u[d]), bfhi(U3.u[d])};
            f32x2 s = v0 * w00 + v1 * w01 + v2 * w10 + v3 * w11;
            A.u[d] = pk2(s[0], s[1]);
        }
        *(bf16x8*)((char*)&sm[ti][px][0] + cb) = A.v;
    }
}

// ---------------------------------------------------------------------------
// GEMM NT taps from sm into acc[2]. wave quadrant: rows px_t, cols via wb0/wb1.
// ---------------------------------------------------------------------------
template<int T0, int NT>
__device__ __forceinline__ void gemm_taps(const short (*__restrict__ sm)[32][72],
                                          f32x4* acc, int px_t, int lg,
                                          const short* __restrict__ wb0,
                                          const short* __restrict__ wb1) {
#pragma unroll
    for (int ti = 0; ti < NT; ++ti) {
#pragma unroll
        for (int h = 0; h < 2; ++h) {
            bf16x8 af = *(const bf16x8*)(&sm[ti][px_t][h * 32 + lg * 8]);
            int k0 = (T0 + ti) * 64 + h * 32 + lg * 8;
            bf16x8 b0 = *(const bf16x8*)(wb0 + k0);
            bf16x8 b1 = *(const bf16x8*)(wb1 + k0);
            acc[0] = __builtin_amdgcn_mfma_f32_16x16x32_bf16(af, b0, acc[0], 0, 0, 0);
            acc[1] = __builtin_amdgcn_mfma_f32_16x16x32_bf16(af, b1, acc[1], 0, 0, 0);
        }
    }
}

// ---------------------------------------------------------------------------
// Fused kernel: 32-pixel tile; K-halved LDS im2col (25.6 KB -> 6 blocks/CU).
// ---------------------------------------------------------------------------
__global__ __launch_bounds__(256, 6) void fused_cl(const short* __restrict__ ws,
                                                   const float* __restrict__ b_off,
                                                   const float* __restrict__ bias,
                                                   float* __restrict__ out) {
    __shared__ short sm[5][32][72];     // K-half im2col (taps subset), 16B-pad rows
    __shared__ float offbuf[32][20];

    int tid = threadIdx.x;
    int wid = tid >> 6;
    int l   = tid & 63;
    int lr  = l & 15;
    int lg  = l >> 4;
    int mhalf = wid >> 1;
    int nhalf = wid & 1;

    // XCD-aware swizzle: nwg = 3200, 3200 % 8 == 0 -> bijective
    int bid = blockIdx.x;
    int g_blk = (bid & 7) * 400 + (bid >> 3);

    int pix_base = g_blk * 32;
    int b   = pix_base / HWp;
    int rem = pix_base - b * HWp;
    int y   = rem / Ww;
    int x0  = rem - y * Ww;            // multiple of 32, row-aligned

    const short* wTb    = ws;
    const short* wToffb = ws + WTB_SHORTS;
    const char*  xclb   = (const char*)(ws + XCL_OFS) + (size_t)b * HWp * 128;

    // ---------------- Phase 1: offset GEMM (1 wave = 1 quadrant) ----------
    {
        int px_t = mhalf * 16 + lr;
        int xpix = x0 + px_t;
        int poff[9];
        unsigned okb = 0;
#pragma unroll
        for (int ty = 0; ty < 3; ++ty) {
#pragma unroll
            for (int tx = 0; tx < 3; ++tx) {
                int t  = ty * 3 + tx;
                int yy = y - 1 + ty;
                int vy = (yy >= 0) && (yy < Hh);
                int yc = min(max(yy, 0), Hh - 1);
                int xx = xpix - 1 + tx;
                int vx = (xx >= 0) && (xx < Ww);
                int xc = min(max(xx, 0), Ww - 1);
                poff[t] = (yc * Ww + xc) * 128;
                okb |= (unsigned)(vy && vx) << t;
            }
        }

        f32x4 accA = {0.f, 0.f, 0.f, 0.f};      // even taps
        f32x4 accB = {0.f, 0.f, 0.f, 0.f};      // odd taps (halved dep chain)
        int oc_row = nhalf * 16 + lr;
        const short* wor = wToffb + (size_t)oc_row * 576;
#pragma unroll
        for (int t = 0; t < 9; ++t) {
            const char* q = xclb + poff[t] + lg * 16;
            bool ok = (okb >> t) & 1u;
#pragma unroll
            for (int h = 0; h < 2; ++h) {
                bf16x8 af = *(const bf16x8*)(q + h * 64);
#pragma unroll
                for (int j = 0; j < 8; ++j)
                    af[j] = ok ? af[j] : (short)0;
                bf16x8 bo = *(const bf16x8*)(wor + t * 64 + h * 32 + lg * 8);
                if (t & 1)
                    accB = __builtin_amdgcn_mfma_f32_16x16x32_bf16(af, bo, accB, 0, 0, 0);
                else
                    accA = __builtin_amdgcn_mfma_f32_16x16x32_bf16(af, bo, accA, 0, 0, 0);
            }
        }
        if (oc_row < 18) {
            float bv = b_off[oc_row];
#pragma unroll
            for (int j = 0; j < 4; ++j)
                offbuf[mhalf * 16 + lg * 4 + j][oc_row] = accA[j] + accB[j] + bv;
        }
    }
    __syncthreads();

    // ---------------- Phases 3a/3b, two K-halves ----------
    int px = tid >> 3;          // 0..31
    int cg = tid & 7;
    int cb = cg * 16;
    int xpix = x0 + px;

    f32x4 acc[2];
    acc[0] = (f32x4){0.f, 0.f, 0.f, 0.f};
    acc[1] = (f32x4){0.f, 0.f, 0.f, 0.f};
    int px_t = mhalf * 16 + lr;
    const short* wb0 = wTb + (size_t)(nhalf * 32 + lr) * 576;
    const short* wb1 = wTb + (size_t)(nhalf * 32 + 16 + lr) * 576;

    // half 0: taps 0..4
    sample_taps<0, 5>(xclb, offbuf, sm, px, cb, y, xpix);
    __syncthreads();
    gemm_taps<0, 5>(sm, acc, px_t, lg, wb0, wb1);
    __syncthreads();

    // half 1: taps 5..8
    sample_taps<5, 4>(xclb, offbuf, sm, px, cb, y, xpix);
    __syncthreads();
    gemm_taps<5, 4>(sm, acc, px_t, lg, wb0, wb1);

    // ---------------- Epilogue ----------------
    float* ob = out + (size_t)b * COUTc * HWp + y * Ww + x0;
#pragma unroll
    for (int nt = 0; nt < 2; ++nt) {
        int o = nhalf * 32 + nt * 16 + lr;
        float bv = bias[o];
#pragma unroll
        for (int j = 0; j < 4; ++j)
            ob[(size_t)o * HWp + mhalf * 16 + lg * 4 + j] = acc[nt][j] + bv;
    }
}

// ---------------------------------------------------------------------------
extern "C" void kernel_launch(void* const* d_in, const int* in_sizes, int n_in,
                              void* d_out, int out_size, void* d_ws, size_t ws_size,
                              hipStream_t stream) {
    const float* x      = (const float*)d_in[0];
    const float* w_off  = (const float*)d_in[1];
    const float* b_off  = (const float*)d_in[2];
    const float* weight = (const float*)d_in[3];
    const float* bias   = (const float*)d_in[4];
    float* outp = (float*)d_out;
    short* ws   = (short*)d_ws;

    // 400 blocks for xcl + 144 blocks for weight images
    prep_all<<<544, 256, 0, stream>>>(x, weight, w_off, ws);

    int nblocks = (Bq * HWp) / 32;   // 3200 workgroups, 32 pixels each
    fused_cl<<<nblocks, 256, 0, stream>>>(ws, b_off, bias, outp);
}